// Round 1
// baseline (1183.662 us; speedup 1.0000x reference)
//
#include <hip/hip_runtime.h>
#include <math.h>

#define B 64
#define S 2048
#define D 512
#define H 512

#define KT 32
#define PAD 68
#define SC 256

// ---------------------------------------------------------------------------
// K1: inp = input @ W_in^T + b_in   -> stored temporarily in d_out hidden region
// ---------------------------------------------------------------------------
__global__ __launch_bounds__(256) void k_input_linear(
        const float* __restrict__ input,
        const float* __restrict__ W_in,
        const float* __restrict__ b_in,
        float* __restrict__ out_inp) {
    const int b = blockIdx.x;
    const int tid = threadIdx.x;
    __shared__ float xrow[D];
    for (int d = tid; d < D; d += 256) xrow[d] = input[(size_t)b * D + d];
    __syncthreads();
    for (int h = tid; h < H; h += 256) {
        const float* w = W_in + (size_t)h * D;
        float acc = 0.f;
        #pragma unroll 4
        for (int d = 0; d < D; d += 4) {
            float4 wv = *(const float4*)(w + d);
            acc += wv.x * xrow[d] + wv.y * xrow[d + 1] + wv.z * xrow[d + 2] + wv.w * xrow[d + 3];
        }
        out_inp[(size_t)b * H + h] = acc + b_in[h];
    }
}

// ---------------------------------------------------------------------------
// K2: fused ctx-GEMM + tanh + V-reduce.
//   For a 64(s) x 64(h) tile: y = context_rows @ Wc^T  (K=512 loop),
//   then att_partial[s] = sum_h V[h] * tanh(inp[b,h] + bc[h] + y[s,h]),
//   atomicAdd into attraw[b,s] (alpha region of d_out, pre-zeroed).
// ---------------------------------------------------------------------------
__global__ __launch_bounds__(256) void k_energy(
        const float* __restrict__ ctx,
        const float* __restrict__ Wc,
        const float* __restrict__ bc,
        const float* __restrict__ inp,
        const float* __restrict__ V,
        float* __restrict__ attraw) {
    __shared__ float As[KT][PAD];   // k-major: As[k][s_local]
    __shared__ float Bs[KT][PAD];   // k-major: Bs[k][h_local]
    __shared__ float red[64][17];

    const int tid = threadIdx.x;
    const int tx = tid & 15;        // h micro index
    const int ty = tid >> 4;        // s micro index
    const int h0 = blockIdx.x * 64;
    const int rowTile = blockIdx.y;
    const int b = rowTile >> 5;             // 32 row-tiles per batch (2048/64)
    const int s0 = (rowTile & 31) * 64;

    const int r8 = tid >> 3;        // 0..31 (row for staging)
    const int kq = tid & 7;         // 0..7  (k-quad for staging)

    float acc[4][4] = {};

    const size_t ctx_base = ((size_t)b * S + s0) * D;

    for (int kt = 0; kt < D; kt += KT) {
        // --- stage A (context rows) and B (Wc rows), transposed to k-major ---
        #pragma unroll
        for (int half = 0; half < 2; ++half) {
            const int r = r8 + half * 32;
            float4 a = *(const float4*)(ctx + ctx_base + (size_t)r * D + kt + kq * 4);
            As[kq * 4 + 0][r] = a.x; As[kq * 4 + 1][r] = a.y;
            As[kq * 4 + 2][r] = a.z; As[kq * 4 + 3][r] = a.w;
            float4 w = *(const float4*)(Wc + (size_t)(h0 + r) * D + kt + kq * 4);
            Bs[kq * 4 + 0][r] = w.x; Bs[kq * 4 + 1][r] = w.y;
            Bs[kq * 4 + 2][r] = w.z; Bs[kq * 4 + 3][r] = w.w;
        }
        __syncthreads();
        // --- inner product over this K-tile ---
        #pragma unroll
        for (int k = 0; k < KT; ++k) {
            float4 a  = *(const float4*)&As[k][ty * 4];
            float4 bv = *(const float4*)&Bs[k][tx * 4];
            float av[4] = {a.x, a.y, a.z, a.w};
            float bw[4] = {bv.x, bv.y, bv.z, bv.w};
            #pragma unroll
            for (int i = 0; i < 4; ++i)
                #pragma unroll
                for (int j = 0; j < 4; ++j)
                    acc[i][j] += av[i] * bw[j];
        }
        __syncthreads();
    }

    // --- epilogue: tanh + V weighting, reduce over h within tile ---
    float ps[4] = {0.f, 0.f, 0.f, 0.f};
    #pragma unroll
    for (int j = 0; j < 4; ++j) {
        const int h = h0 + tx * 4 + j;
        const float ib = inp[(size_t)b * H + h] + bc[h];
        const float v = V[h];
        #pragma unroll
        for (int i = 0; i < 4; ++i)
            ps[i] += v * tanhf(acc[i][j] + ib);
    }
    #pragma unroll
    for (int i = 0; i < 4; ++i) red[ty * 4 + i][tx] = ps[i];
    __syncthreads();
    if (tid < 64) {
        float sum = 0.f;
        #pragma unroll
        for (int t = 0; t < 16; ++t) sum += red[tid][t];
        atomicAdd(attraw + (size_t)b * S + s0 + tid, sum);
    }
}

// ---------------------------------------------------------------------------
// K4: mask branch + softmax per row (in place in the alpha region).
//     Recomputes global n_true = sum(mask != 0) per block (cheap, L2/L3).
// ---------------------------------------------------------------------------
__global__ __launch_bounds__(256) void k_softmax(
        const int* __restrict__ mask,
        const float* __restrict__ amask,
        float* __restrict__ att) {
    const int b = blockIdx.x;
    const int tid = threadIdx.x;
    __shared__ float sh[S];
    __shared__ int ired[4];
    __shared__ float fredm[4];
    __shared__ float freds[4];

    // global mask count (over the whole [B,S] mask, per reference)
    int local = 0;
    for (int i = tid; i < B * S; i += 256) local += (mask[i] != 0) ? 1 : 0;
    #pragma unroll
    for (int off = 32; off; off >>= 1) local += __shfl_down(local, off, 64);
    if ((tid & 63) == 0) ired[tid >> 6] = local;
    __syncthreads();
    const int n_true = ired[0] + ired[1] + ired[2] + ired[3];
    const bool inf_branch = (n_true > 0) && (n_true == S);

    const float NEG_INF = -__builtin_inff();
    for (int s = tid; s < S; s += 256) {
        const float raw = att[(size_t)b * S + s];
        float v;
        if (inf_branch)
            v = mask[(size_t)b * S + s] ? NEG_INF : raw;
        else
            v = raw * amask[(size_t)b * S + s];
        sh[s] = v;
    }
    __syncthreads();

    // max reduce
    float mx = NEG_INF;
    for (int s = tid; s < S; s += 256) mx = fmaxf(mx, sh[s]);
    #pragma unroll
    for (int off = 32; off; off >>= 1) mx = fmaxf(mx, __shfl_down(mx, off, 64));
    if ((tid & 63) == 0) fredm[tid >> 6] = mx;
    __syncthreads();
    mx = fmaxf(fmaxf(fredm[0], fredm[1]), fmaxf(fredm[2], fredm[3]));

    // exp + sum reduce
    float lsum = 0.f;
    for (int s = tid; s < S; s += 256) {
        const float e = expf(sh[s] - mx);
        sh[s] = e;
        lsum += e;
    }
    #pragma unroll
    for (int off = 32; off; off >>= 1) lsum += __shfl_down(lsum, off, 64);
    if ((tid & 63) == 0) freds[tid >> 6] = lsum;
    __syncthreads();
    const float total = freds[0] + freds[1] + freds[2] + freds[3];
    const float rinv = 1.f / total;

    for (int s = tid; s < S; s += 256)
        att[(size_t)b * S + s] = sh[s] * rinv;
}

// ---------------------------------------------------------------------------
// K56: hidden = Wc @ (sum_s alpha[b,s] * context[b,s,:]) + bc
//   Each block: one (b, s-chunk of SC rows). Partial weighted context sum in
//   LDS, then partial Wc@cbar atomicAdd'ed into hidden (pre-zeroed).
// ---------------------------------------------------------------------------
__global__ __launch_bounds__(256) void k_context_out(
        const float* __restrict__ ctx,
        const float* __restrict__ alpha,
        const float* __restrict__ Wc,
        const float* __restrict__ bc,
        float* __restrict__ hidden) {
    const int chunk = blockIdx.x;  // 0..S/SC-1
    const int b = blockIdx.y;
    const int tid = threadIdx.x;
    const int s0 = chunk * SC;
    __shared__ float al[SC];
    __shared__ float cb[D];

    al[tid] = alpha[(size_t)b * S + s0 + tid];
    __syncthreads();

    float c0 = 0.f, c1 = 0.f;
    const float* base = ctx + ((size_t)b * S + s0) * D + tid * 2;
    for (int s = 0; s < SC; ++s) {
        const float2 v = *(const float2*)(base + (size_t)s * D);
        const float a = al[s];
        c0 += a * v.x;
        c1 += a * v.y;
    }
    cb[tid * 2] = c0;
    cb[tid * 2 + 1] = c1;
    __syncthreads();

    #pragma unroll
    for (int hh = 0; hh < 2; ++hh) {
        const int h = tid + hh * 256;
        const float* w = Wc + (size_t)h * D;
        float acc = 0.f;
        #pragma unroll 4
        for (int d = 0; d < D; d += 4) {
            float4 wv = *(const float4*)(w + d);
            acc += wv.x * cb[d] + wv.y * cb[d + 1] + wv.z * cb[d + 2] + wv.w * cb[d + 3];
        }
        if (chunk == 0) acc += bc[h];
        atomicAdd(hidden + (size_t)b * H + h, acc);
    }
}

// ---------------------------------------------------------------------------
extern "C" void kernel_launch(void* const* d_in, const int* in_sizes, int n_in,
                              void* d_out, int out_size, void* d_ws, size_t ws_size,
                              hipStream_t stream) {
    const float* input = (const float*)d_in[0];
    const float* ctx   = (const float*)d_in[1];
    const float* amask = (const float*)d_in[2];
    const float* W_in  = (const float*)d_in[3];
    const float* b_in  = (const float*)d_in[4];
    const float* W_ctx = (const float*)d_in[5];
    const float* b_ctx = (const float*)d_in[6];
    const float* V     = (const float*)d_in[7];
    const int*   mask  = (const int*)d_in[8];

    float* out = (float*)d_out;
    float* hidden = out;            // [B,H]   (first output)
    float* alpha  = out + B * H;    // [B,S]   (second output)

    // attraw accumulates in the alpha region: zero it (deterministic each call)
    hipMemsetAsync(alpha, 0, (size_t)B * S * sizeof(float), stream);

    // K1: inp staged in the hidden region (overwritten later by real hidden)
    k_input_linear<<<dim3(B), dim3(256), 0, stream>>>(input, W_in, b_in, hidden);

    // K2: fused energy GEMM (+tanh +V reduce) -> attraw (alpha region)
    k_energy<<<dim3(H / 64, (B * S) / 64), dim3(256), 0, stream>>>(
        ctx, W_ctx, b_ctx, hidden, V, alpha);

    // K4: mask branch + softmax in place -> alpha final
    k_softmax<<<dim3(B), dim3(256), 0, stream>>>(mask, amask, alpha);

    // hidden region now free (inp consumed): zero and accumulate
    hipMemsetAsync(hidden, 0, (size_t)B * H * sizeof(float), stream);

    // K56: weighted context average + output projection -> hidden final
    k_context_out<<<dim3(S / SC, B), dim3(256), 0, stream>>>(
        ctx, alpha, W_ctx, b_ctx, hidden);
}

// Round 3
// 404.130 us; speedup vs baseline: 2.9289x; 2.9289x over previous
//
#include <hip/hip_runtime.h>
#include <math.h>

#define B 64
#define S 2048
#define D 512
#define H 512

#define SC 256

typedef _Float16 f16x8 __attribute__((ext_vector_type(8)));
typedef __fp16 fp16x2 __attribute__((ext_vector_type(2)));
typedef float f32x4 __attribute__((ext_vector_type(4)));

#define LDA 40  // padded row stride in halfs (80 B): rows 0..7 -> 8 distinct bank groups

// ---------------------------------------------------------------------------
// K1: inp = input @ W_in^T + b_in   -> stored temporarily in d_out hidden region
// ---------------------------------------------------------------------------
__global__ __launch_bounds__(256) void k_input_linear(
        const float* __restrict__ input,
        const float* __restrict__ W_in,
        const float* __restrict__ b_in,
        float* __restrict__ out_inp) {
    const int b = blockIdx.x;
    const int tid = threadIdx.x;
    __shared__ float xrow[D];
    for (int d = tid; d < D; d += 256) xrow[d] = input[(size_t)b * D + d];
    __syncthreads();
    for (int h = tid; h < H; h += 256) {
        const float* w = W_in + (size_t)h * D;
        float acc = 0.f;
        #pragma unroll 4
        for (int d = 0; d < D; d += 4) {
            float4 wv = *(const float4*)(w + d);
            acc += wv.x * xrow[d] + wv.y * xrow[d + 1] + wv.z * xrow[d + 2] + wv.w * xrow[d + 3];
        }
        out_inp[(size_t)b * H + h] = acc + b_in[h];
    }
}

// ---------------------------------------------------------------------------
// K2 (MFMA): fused ctx-GEMM + tanh + V-reduce, full-H per block.
//   Block: 128 s-rows x 512 h, 512 threads = 8 waves (2s x 4h), wave 64x128.
//   fp32 context/Wc converted to fp16 on the fly (cvt_pkrtz), K-step 32.
//   att written directly (no atomics).
// ---------------------------------------------------------------------------
__global__ __launch_bounds__(512) void k_energy(
        const float* __restrict__ ctx,
        const float* __restrict__ Wc,
        const float* __restrict__ bc,
        const float* __restrict__ inp,
        const float* __restrict__ V,
        float* __restrict__ att) {
    __shared__ alignas(16) _Float16 Alds[128 * LDA];
    __shared__ alignas(16) _Float16 Blds[512 * LDA];
    __shared__ float red[4][128];

    const int tid = threadIdx.x;
    const int b = blockIdx.x >> 4;
    const int s0 = (blockIdx.x & 15) << 7;

    // staging roles: 4 threads per row, each handles 8 consecutive k (16 B)
    const int arow = tid >> 2;      // 0..127
    const int akq  = tid & 3;       // 0..3 -> k offset akq*8

    // wave/compute roles
    const int lane = tid & 63;
    const int w    = tid >> 6;      // 0..7
    const int ws   = w & 1;         // s-half of block
    const int wh   = w >> 1;        // 0..3, h-quarter (128 h each)
    const int lrow = lane & 15;
    const int kblk = lane >> 4;     // 0..3 -> k offset kblk*8

    f32x4 acc[4][8] = {};

    const size_t ctx_row0 = ((size_t)b * S + s0 + arow) * D;
    const _Float16* Abase = &Alds[(ws * 64 + lrow) * LDA + kblk * 8];
    const _Float16* Bbase = &Blds[(wh * 128 + lrow) * LDA + kblk * 8];

    #pragma unroll 1
    for (int kt = 0; kt < D; kt += 32) {
        // ---- stage A: 128 rows x 32 k ----
        {
            const float* src = ctx + ctx_row0 + kt + akq * 8;
            float4 f0 = *(const float4*)src;
            float4 f1 = *(const float4*)(src + 4);
            union { fp16x2 h2[4]; f16x8 v; } u;
            u.h2[0] = __builtin_amdgcn_cvt_pkrtz(f0.x, f0.y);
            u.h2[1] = __builtin_amdgcn_cvt_pkrtz(f0.z, f0.w);
            u.h2[2] = __builtin_amdgcn_cvt_pkrtz(f1.x, f1.y);
            u.h2[3] = __builtin_amdgcn_cvt_pkrtz(f1.z, f1.w);
            *(f16x8*)&Alds[arow * LDA + akq * 8] = u.v;
        }
        // ---- stage B: 512 rows x 32 k ----
        #pragma unroll
        for (int i = 0; i < 4; ++i) {
            const int hrow = arow + i * 128;
            const float* src = Wc + (size_t)hrow * D + kt + akq * 8;
            float4 f0 = *(const float4*)src;
            float4 f1 = *(const float4*)(src + 4);
            union { fp16x2 h2[4]; f16x8 v; } u;
            u.h2[0] = __builtin_amdgcn_cvt_pkrtz(f0.x, f0.y);
            u.h2[1] = __builtin_amdgcn_cvt_pkrtz(f0.z, f0.w);
            u.h2[2] = __builtin_amdgcn_cvt_pkrtz(f1.x, f1.y);
            u.h2[3] = __builtin_amdgcn_cvt_pkrtz(f1.z, f1.w);
            *(f16x8*)&Blds[hrow * LDA + akq * 8] = u.v;
        }
        __syncthreads();

        // ---- MFMA: wave tile 64s x 128h, one K=32 step ----
        f16x8 afr[4];
        #pragma unroll
        for (int m = 0; m < 4; ++m)
            afr[m] = *(const f16x8*)(Abase + m * 16 * LDA);
        f16x8 bfr[8];
        #pragma unroll
        for (int n = 0; n < 8; ++n)
            bfr[n] = *(const f16x8*)(Bbase + n * 16 * LDA);
        #pragma unroll
        for (int m = 0; m < 4; ++m)
            #pragma unroll
            for (int n = 0; n < 8; ++n)
                acc[m][n] = __builtin_amdgcn_mfma_f32_16x16x32_f16(afr[m], bfr[n], acc[m][n], 0, 0, 0);
        __syncthreads();
    }

    // ---- epilogue: tanh + V weighting; reduce over h ----
    float ps[4][4] = {};   // [m][reg]
    #pragma unroll
    for (int n = 0; n < 8; ++n) {
        const int h = wh * 128 + n * 16 + lrow;
        const float ib = inp[(size_t)b * H + h] + bc[h];
        const float v = V[h];
        #pragma unroll
        for (int m = 0; m < 4; ++m)
            #pragma unroll
            for (int r = 0; r < 4; ++r) {
                const float x = acc[m][n][r] + ib;
                const float t = 1.f - 2.f / (1.f + __expf(2.f * x));
                ps[m][r] += v * t;
            }
    }
    // reduce across the 16 cols held by lanes (same row group)
    #pragma unroll
    for (int off = 1; off < 16; off <<= 1)
        #pragma unroll
        for (int m = 0; m < 4; ++m)
            #pragma unroll
            for (int r = 0; r < 4; ++r)
                ps[m][r] += __shfl_xor(ps[m][r], off, 64);
    if (lrow == 0) {
        #pragma unroll
        for (int m = 0; m < 4; ++m)
            #pragma unroll
            for (int r = 0; r < 4; ++r)
                red[wh][ws * 64 + m * 16 + kblk * 4 + r] = ps[m][r];
    }
    __syncthreads();
    if (tid < 128) {
        const float sum = red[0][tid] + red[1][tid] + red[2][tid] + red[3][tid];
        att[(size_t)b * S + s0 + tid] = sum;
    }
}

// ---------------------------------------------------------------------------
// K4: mask branch + softmax per row (in place in the alpha region).
// ---------------------------------------------------------------------------
__global__ __launch_bounds__(256) void k_softmax(
        const int* __restrict__ mask,
        const float* __restrict__ amask,
        float* __restrict__ att) {
    const int b = blockIdx.x;
    const int tid = threadIdx.x;
    __shared__ float sh[S];
    __shared__ int ired[4];
    __shared__ float fredm[4];
    __shared__ float freds[4];

    int local = 0;
    for (int i = tid; i < B * S; i += 256) local += (mask[i] != 0) ? 1 : 0;
    #pragma unroll
    for (int off = 32; off; off >>= 1) local += __shfl_down(local, off, 64);
    if ((tid & 63) == 0) ired[tid >> 6] = local;
    __syncthreads();
    const int n_true = ired[0] + ired[1] + ired[2] + ired[3];
    const bool inf_branch = (n_true > 0) && (n_true == S);

    const float NEG_INF = -__builtin_inff();
    for (int s = tid; s < S; s += 256) {
        const float raw = att[(size_t)b * S + s];
        float v;
        if (inf_branch)
            v = mask[(size_t)b * S + s] ? NEG_INF : raw;
        else
            v = raw * amask[(size_t)b * S + s];
        sh[s] = v;
    }
    __syncthreads();

    float mx = NEG_INF;
    for (int s = tid; s < S; s += 256) mx = fmaxf(mx, sh[s]);
    #pragma unroll
    for (int off = 32; off; off >>= 1) mx = fmaxf(mx, __shfl_down(mx, off, 64));
    if ((tid & 63) == 0) fredm[tid >> 6] = mx;
    __syncthreads();
    mx = fmaxf(fmaxf(fredm[0], fredm[1]), fmaxf(fredm[2], fredm[3]));

    float lsum = 0.f;
    for (int s = tid; s < S; s += 256) {
        const float e = expf(sh[s] - mx);
        sh[s] = e;
        lsum += e;
    }
    #pragma unroll
    for (int off = 32; off; off >>= 1) lsum += __shfl_down(lsum, off, 64);
    if ((tid & 63) == 0) freds[tid >> 6] = lsum;
    __syncthreads();
    const float total = freds[0] + freds[1] + freds[2] + freds[3];
    const float rinv = 1.f / total;

    for (int s = tid; s < S; s += 256)
        att[(size_t)b * S + s] = sh[s] * rinv;
}

// ---------------------------------------------------------------------------
// K56: hidden = Wc @ (sum_s alpha[b,s] * context[b,s,:]) + bc
// ---------------------------------------------------------------------------
__global__ __launch_bounds__(256) void k_context_out(
        const float* __restrict__ ctx,
        const float* __restrict__ alpha,
        const float* __restrict__ Wc,
        const float* __restrict__ bc,
        float* __restrict__ hidden) {
    const int chunk = blockIdx.x;  // 0..S/SC-1
    const int b = blockIdx.y;
    const int tid = threadIdx.x;
    const int s0 = chunk * SC;
    __shared__ float al[SC];
    __shared__ float cb[D];

    al[tid] = alpha[(size_t)b * S + s0 + tid];
    __syncthreads();

    float c0 = 0.f, c1 = 0.f;
    const float* base = ctx + ((size_t)b * S + s0) * D + tid * 2;
    for (int s = 0; s < SC; ++s) {
        const float2 v = *(const float2*)(base + (size_t)s * D);
        const float a = al[s];
        c0 += a * v.x;
        c1 += a * v.y;
    }
    cb[tid * 2] = c0;
    cb[tid * 2 + 1] = c1;
    __syncthreads();

    #pragma unroll
    for (int hh = 0; hh < 2; ++hh) {
        const int h = tid + hh * 256;
        const float* w = Wc + (size_t)h * D;
        float acc = 0.f;
        #pragma unroll 4
        for (int d = 0; d < D; d += 4) {
            float4 wv = *(const float4*)(w + d);
            acc += wv.x * cb[d] + wv.y * cb[d + 1] + wv.z * cb[d + 2] + wv.w * cb[d + 3];
        }
        if (chunk == 0) acc += bc[h];
        atomicAdd(hidden + (size_t)b * H + h, acc);
    }
}

// ---------------------------------------------------------------------------
extern "C" void kernel_launch(void* const* d_in, const int* in_sizes, int n_in,
                              void* d_out, int out_size, void* d_ws, size_t ws_size,
                              hipStream_t stream) {
    const float* input = (const float*)d_in[0];
    const float* ctx   = (const float*)d_in[1];
    const float* amask = (const float*)d_in[2];
    const float* W_in  = (const float*)d_in[3];
    const float* b_in  = (const float*)d_in[4];
    const float* W_ctx = (const float*)d_in[5];
    const float* b_ctx = (const float*)d_in[6];
    const float* V     = (const float*)d_in[7];
    const int*   mask  = (const int*)d_in[8];

    float* out = (float*)d_out;
    float* hidden = out;            // [B,H]   (first output)
    float* alpha  = out + B * H;    // [B,S]   (second output)

    // K1: inp staged in the hidden region (overwritten later by real hidden)
    k_input_linear<<<dim3(B), dim3(256), 0, stream>>>(input, W_in, b_in, hidden);

    // K2: fused energy GEMM (MFMA fp16) + tanh + V reduce -> att (alpha region)
    k_energy<<<dim3((B * S) / 128), dim3(512), 0, stream>>>(
        ctx, W_ctx, b_ctx, hidden, V, alpha);

    // K4: mask branch + softmax in place -> alpha final
    k_softmax<<<dim3(B), dim3(256), 0, stream>>>(mask, amask, alpha);

    // hidden region now free (inp consumed): zero and accumulate
    (void)hipMemsetAsync(hidden, 0, (size_t)B * H * sizeof(float), stream);

    // K56: weighted context average + output projection -> hidden final
    k_context_out<<<dim3(S / SC, B), dim3(256), 0, stream>>>(
        ctx, alpha, W_ctx, b_ctx, hidden);
}

// Round 4
// 364.401 us; speedup vs baseline: 3.2482x; 1.1090x over previous
//
#include <hip/hip_runtime.h>
#include <math.h>

#define B 64
#define S 2048
#define D 512
#define H 512

typedef _Float16 f16x8 __attribute__((ext_vector_type(8)));
typedef __fp16 fp16x2 __attribute__((ext_vector_type(2)));
typedef float f32x4 __attribute__((ext_vector_type(4)));

#define LDA 40   // A-tile padded row stride in halfs (80 B, 16B-aligned, 2-way-free banks)
#define WSC 128  // s-rows per k_wsum block

// ws layout: [0, 512KB) = Wc packed fp16 fragment-order; [512KB, 640KB) = cbar f32 [B][D]
#define WS_CBAR_OFF (512 * 1024)

// ---------------------------------------------------------------------------
// K0: pack Wc (fp32 [H][D]) -> fp16 in MFMA-fragment order.
//   slot = kt*2048 + hg*64 + lane ; holds Wc[hg*16 + (lane&15)][kt*32 + (lane>>4)*8 + j]
// ---------------------------------------------------------------------------
__global__ __launch_bounds__(256) void k_pack_wc(
        const float* __restrict__ Wc, _Float16* __restrict__ wsB) {
    const int slot = blockIdx.x * 256 + threadIdx.x;   // 0..32767
    const int kt   = slot >> 11;
    const int rem  = slot & 2047;
    const int hg   = rem >> 6;
    const int lane = rem & 63;
    const int h  = hg * 16 + (lane & 15);
    const int k0 = kt * 32 + (lane >> 4) * 8;
    const float* src = Wc + (size_t)h * D + k0;
    float4 f0 = *(const float4*)src;
    float4 f1 = *(const float4*)(src + 4);
    f16x8 v;
    v[0] = (_Float16)f0.x; v[1] = (_Float16)f0.y;
    v[2] = (_Float16)f0.z; v[3] = (_Float16)f0.w;
    v[4] = (_Float16)f1.x; v[5] = (_Float16)f1.y;
    v[6] = (_Float16)f1.z; v[7] = (_Float16)f1.w;
    *(f16x8*)(wsB + (size_t)slot * 8) = v;
}

// ---------------------------------------------------------------------------
// K1: inp = input @ W_in^T + b_in   -> stored temporarily in d_out hidden region
// ---------------------------------------------------------------------------
__global__ __launch_bounds__(256) void k_input_linear(
        const float* __restrict__ input,
        const float* __restrict__ W_in,
        const float* __restrict__ b_in,
        float* __restrict__ out_inp) {
    const int b = blockIdx.x;
    const int tid = threadIdx.x;
    __shared__ float xrow[D];
    for (int d = tid; d < D; d += 256) xrow[d] = input[(size_t)b * D + d];
    __syncthreads();
    for (int h = tid; h < H; h += 256) {
        const float* w = W_in + (size_t)h * D;
        float acc = 0.f;
        #pragma unroll 4
        for (int d = 0; d < D; d += 4) {
            float4 wv = *(const float4*)(w + d);
            acc += wv.x * xrow[d] + wv.y * xrow[d + 1] + wv.z * xrow[d + 2] + wv.w * xrow[d + 3];
        }
        out_inp[(size_t)b * H + h] = acc + b_in[h];
    }
}

// ---------------------------------------------------------------------------
// K2 (MFMA): fused ctx-GEMM + tanh + V-reduce, full-H per block.
//   128 s-rows x 512 h, 512 threads = 8 waves (2s x 4h), wave tile 64x128.
//   A: ctx fp32 -> cvt_pkrtz -> LDS (padded). B: pre-packed fp16 frags -> LDS
//   (linear, conflict-free). T14: next-tile loads issued before MFMAs.
// ---------------------------------------------------------------------------
__global__ __launch_bounds__(512) void k_energy(
        const float* __restrict__ ctx,
        const _Float16* __restrict__ WcP,
        const float* __restrict__ bc,
        const float* __restrict__ inp,
        const float* __restrict__ V,
        float* __restrict__ att) {
    __shared__ alignas(16) _Float16 Alds[128 * LDA];   // 10240 B
    __shared__ alignas(16) _Float16 Blds[16384];       // 32 KB frag-order [hg][lane][8]
    __shared__ float red[4][128];

    const int tid = threadIdx.x;
    const int b  = blockIdx.x >> 4;
    const int s0 = (blockIdx.x & 15) << 7;

    // staging roles
    const int arow = tid >> 2;      // 0..127
    const int akq  = tid & 3;       // 0..3 -> 8 halfs each
    // compute roles
    const int lane = tid & 63;
    const int w    = tid >> 6;
    const int ws   = w & 1;         // s-half
    const int wh   = w >> 1;        // h-quarter
    const int lrow = lane & 15;
    const int kblk = lane >> 4;

    f32x4 acc[4][8] = {};

    const size_t ctx_row0 = ((size_t)b * S + s0 + arow) * D;
    const _Float16* Abase = &Alds[(ws * 64 + lrow) * LDA + kblk * 8];

    // ---- prologue: stage kt=0 ----
    {
        float4 f0 = *(const float4*)(ctx + ctx_row0 + akq * 8);
        float4 f1 = *(const float4*)(ctx + ctx_row0 + akq * 8 + 4);
        union { fp16x2 h2[4]; f16x8 v; } u;
        u.h2[0] = __builtin_amdgcn_cvt_pkrtz(f0.x, f0.y);
        u.h2[1] = __builtin_amdgcn_cvt_pkrtz(f0.z, f0.w);
        u.h2[2] = __builtin_amdgcn_cvt_pkrtz(f1.x, f1.y);
        u.h2[3] = __builtin_amdgcn_cvt_pkrtz(f1.z, f1.w);
        *(f16x8*)&Alds[arow * LDA + akq * 8] = u.v;
        #pragma unroll
        for (int i = 0; i < 4; ++i) {
            const int unit = i * 512 + tid;
            f16x8 bv = *(const f16x8*)(WcP + (size_t)unit * 8);
            *(f16x8*)&Blds[unit * 8] = bv;
        }
    }

    #pragma unroll 1
    for (int kt = 0; kt < 16; ++kt) {
        __syncthreads();   // staged tile kt visible

        // ---- issue next-tile loads into regs (latency hidden under MFMA) ----
        float4 nf0, nf1;
        f16x8 nb[4];
        if (kt < 15) {
            const float* asrc = ctx + ctx_row0 + (kt + 1) * 32 + akq * 8;
            nf0 = *(const float4*)asrc;
            nf1 = *(const float4*)(asrc + 4);
            #pragma unroll
            for (int i = 0; i < 4; ++i) {
                const int unit = i * 512 + tid;
                nb[i] = *(const f16x8*)(WcP + (size_t)(kt + 1) * 16384 + (size_t)unit * 8);
            }
        }

        // ---- compute tile kt ----
        f16x8 afr[4];
        #pragma unroll
        for (int m = 0; m < 4; ++m)
            afr[m] = *(const f16x8*)(Abase + m * 16 * LDA);
        f16x8 bfr[8];
        #pragma unroll
        for (int n = 0; n < 8; ++n)
            bfr[n] = *(const f16x8*)&Blds[(wh * 8 + n) * 512 + lane * 8];
        #pragma unroll
        for (int m = 0; m < 4; ++m)
            #pragma unroll
            for (int n = 0; n < 8; ++n)
                acc[m][n] = __builtin_amdgcn_mfma_f32_16x16x32_f16(afr[m], bfr[n], acc[m][n], 0, 0, 0);

        __syncthreads();   // all reads of tile kt done

        // ---- write next tile to LDS ----
        if (kt < 15) {
            union { fp16x2 h2[4]; f16x8 v; } u;
            u.h2[0] = __builtin_amdgcn_cvt_pkrtz(nf0.x, nf0.y);
            u.h2[1] = __builtin_amdgcn_cvt_pkrtz(nf0.z, nf0.w);
            u.h2[2] = __builtin_amdgcn_cvt_pkrtz(nf1.x, nf1.y);
            u.h2[3] = __builtin_amdgcn_cvt_pkrtz(nf1.z, nf1.w);
            *(f16x8*)&Alds[arow * LDA + akq * 8] = u.v;
            #pragma unroll
            for (int i = 0; i < 4; ++i) {
                const int unit = i * 512 + tid;
                *(f16x8*)&Blds[unit * 8] = nb[i];
            }
        }
    }

    // ---- epilogue: tanh + V weighting; reduce over h ----
    float ps[4][4] = {};   // [m][reg]
    #pragma unroll
    for (int n = 0; n < 8; ++n) {
        const int h = wh * 128 + n * 16 + lrow;
        const float ib = inp[(size_t)b * H + h] + bc[h];
        const float v = V[h];
        #pragma unroll
        for (int m = 0; m < 4; ++m)
            #pragma unroll
            for (int r = 0; r < 4; ++r) {
                const float x = acc[m][n][r] + ib;
                const float t = 1.f - 2.f / (1.f + __expf(2.f * x));
                ps[m][r] += v * t;
            }
    }
    #pragma unroll
    for (int off = 1; off < 16; off <<= 1)
        #pragma unroll
        for (int m = 0; m < 4; ++m)
            #pragma unroll
            for (int r = 0; r < 4; ++r)
                ps[m][r] += __shfl_xor(ps[m][r], off, 64);
    if (lrow == 0) {
        #pragma unroll
        for (int m = 0; m < 4; ++m)
            #pragma unroll
            for (int r = 0; r < 4; ++r)
                red[wh][ws * 64 + m * 16 + kblk * 4 + r] = ps[m][r];
    }
    __syncthreads();
    if (tid < 128) {
        const float sum = red[0][tid] + red[1][tid] + red[2][tid] + red[3][tid];
        att[(size_t)b * S + s0 + tid] = sum;
    }
}

// ---------------------------------------------------------------------------
// K4: mask branch + softmax per row (in place in the alpha region).
// ---------------------------------------------------------------------------
__global__ __launch_bounds__(256) void k_softmax(
        const int* __restrict__ mask,
        const float* __restrict__ amask,
        float* __restrict__ att) {
    const int b = blockIdx.x;
    const int tid = threadIdx.x;
    __shared__ float sh[S];
    __shared__ int ired[4];
    __shared__ float fredm[4];
    __shared__ float freds[4];

    int local = 0;
    for (int i = tid; i < B * S; i += 256) local += (mask[i] != 0) ? 1 : 0;
    #pragma unroll
    for (int off = 32; off; off >>= 1) local += __shfl_down(local, off, 64);
    if ((tid & 63) == 0) ired[tid >> 6] = local;
    __syncthreads();
    const int n_true = ired[0] + ired[1] + ired[2] + ired[3];
    const bool inf_branch = (n_true > 0) && (n_true == S);

    const float NEG_INF = -__builtin_inff();
    for (int s = tid; s < S; s += 256) {
        const float raw = att[(size_t)b * S + s];
        float v;
        if (inf_branch)
            v = mask[(size_t)b * S + s] ? NEG_INF : raw;
        else
            v = raw * amask[(size_t)b * S + s];
        sh[s] = v;
    }
    __syncthreads();

    float mx = NEG_INF;
    for (int s = tid; s < S; s += 256) mx = fmaxf(mx, sh[s]);
    #pragma unroll
    for (int off = 32; off; off >>= 1) mx = fmaxf(mx, __shfl_down(mx, off, 64));
    if ((tid & 63) == 0) fredm[tid >> 6] = mx;
    __syncthreads();
    mx = fmaxf(fmaxf(fredm[0], fredm[1]), fmaxf(fredm[2], fredm[3]));

    float lsum = 0.f;
    for (int s = tid; s < S; s += 256) {
        const float e = expf(sh[s] - mx);
        sh[s] = e;
        lsum += e;
    }
    #pragma unroll
    for (int off = 32; off; off >>= 1) lsum += __shfl_down(lsum, off, 64);
    if ((tid & 63) == 0) freds[tid >> 6] = lsum;
    __syncthreads();
    const float total = freds[0] + freds[1] + freds[2] + freds[3];
    const float rinv = 1.f / total;

    for (int s = tid; s < S; s += 256)
        att[(size_t)b * S + s] = sh[s] * rinv;
}

// ---------------------------------------------------------------------------
// K5: cbar[b,:] += sum_s alpha[b,s] * ctx[b,s,:]  (streaming, atomic partials)
// ---------------------------------------------------------------------------
__global__ __launch_bounds__(256) void k_wsum(
        const float* __restrict__ ctx,
        const float* __restrict__ alpha,
        float* __restrict__ cbar) {
    const int chunk = blockIdx.x & 15;   // 16 chunks of WSC rows
    const int b = blockIdx.x >> 4;
    const int s0 = chunk * WSC;
    const int tid = threadIdx.x;
    __shared__ float al[WSC];
    if (tid < WSC) al[tid] = alpha[(size_t)b * S + s0 + tid];
    __syncthreads();

    const int half = tid >> 7;           // 0/1: row parity
    const int dq = (tid & 127) * 4;      // d quad
    const float* base = ctx + ((size_t)b * S + s0 + half) * D + dq;
    float4 acc = {0.f, 0.f, 0.f, 0.f};
    #pragma unroll 4
    for (int i = 0; i < WSC / 2; ++i) {
        float4 v = *(const float4*)(base + (size_t)i * 2 * D);
        const float a = al[i * 2 + half];
        acc.x += a * v.x; acc.y += a * v.y; acc.z += a * v.z; acc.w += a * v.w;
    }
    float* dst = cbar + (size_t)b * D + dq;
    atomicAdd(dst + 0, acc.x);
    atomicAdd(dst + 1, acc.y);
    atomicAdd(dst + 2, acc.z);
    atomicAdd(dst + 3, acc.w);
}

// ---------------------------------------------------------------------------
// K6: hidden = Wc @ cbar + bc   (tiny GEMV per batch)
// ---------------------------------------------------------------------------
__global__ __launch_bounds__(256) void k_out(
        const float* __restrict__ cbar,
        const float* __restrict__ Wc,
        const float* __restrict__ bc,
        float* __restrict__ hidden) {
    const int b = blockIdx.x;
    const int tid = threadIdx.x;
    __shared__ float cb[D];
    for (int d = tid; d < D; d += 256) cb[d] = cbar[(size_t)b * D + d];
    __syncthreads();
    for (int h = tid; h < H; h += 256) {
        const float* w = Wc + (size_t)h * D;
        float acc = 0.f;
        #pragma unroll 4
        for (int d = 0; d < D; d += 4) {
            float4 wv = *(const float4*)(w + d);
            acc += wv.x * cb[d] + wv.y * cb[d + 1] + wv.z * cb[d + 2] + wv.w * cb[d + 3];
        }
        hidden[(size_t)b * H + h] = acc + bc[h];
    }
}

// ---------------------------------------------------------------------------
extern "C" void kernel_launch(void* const* d_in, const int* in_sizes, int n_in,
                              void* d_out, int out_size, void* d_ws, size_t ws_size,
                              hipStream_t stream) {
    const float* input = (const float*)d_in[0];
    const float* ctx   = (const float*)d_in[1];
    const float* amask = (const float*)d_in[2];
    const float* W_in  = (const float*)d_in[3];
    const float* b_in  = (const float*)d_in[4];
    const float* W_ctx = (const float*)d_in[5];
    const float* b_ctx = (const float*)d_in[6];
    const float* V     = (const float*)d_in[7];
    const int*   mask  = (const int*)d_in[8];

    float* out = (float*)d_out;
    float* hidden = out;            // [B,H]   (first output)
    float* alpha  = out + B * H;    // [B,S]   (second output)

    _Float16* wsB  = (_Float16*)d_ws;                          // 512 KB packed Wc
    float*    cbar = (float*)((char*)d_ws + WS_CBAR_OFF);      // 128 KB

    // K0: pack Wc -> fp16 fragment order
    k_pack_wc<<<dim3(128), dim3(256), 0, stream>>>(W_ctx, wsB);

    // K1: inp staged in the hidden region (overwritten later by real hidden)
    k_input_linear<<<dim3(B), dim3(256), 0, stream>>>(input, W_in, b_in, hidden);

    // K2: fused energy GEMM (MFMA fp16) + tanh + V reduce -> att (alpha region)
    k_energy<<<dim3((B * S) / 128), dim3(512), 0, stream>>>(
        ctx, wsB, b_ctx, hidden, V, alpha);

    // K4: mask branch + softmax in place -> alpha final
    k_softmax<<<dim3(B), dim3(256), 0, stream>>>(mask, amask, alpha);

    // K5: weighted context sum -> cbar (zeroed first)
    (void)hipMemsetAsync(cbar, 0, (size_t)B * D * sizeof(float), stream);
    k_wsum<<<dim3(16 * B), dim3(256), 0, stream>>>(ctx, alpha, cbar);

    // K6: hidden = Wc @ cbar + bc
    k_out<<<dim3(B), dim3(256), 0, stream>>>(cbar, W_ctx, b_ctx, hidden);
}

// Round 5
// 256.605 us; speedup vs baseline: 4.6128x; 1.4201x over previous
//
#include <hip/hip_runtime.h>
#include <math.h>

#define B 64
#define S 2048
#define D 512
#define H 512

typedef _Float16 f16x8 __attribute__((ext_vector_type(8)));
typedef __fp16 fp16x2 __attribute__((ext_vector_type(2)));
typedef float f32x4 __attribute__((ext_vector_type(4)));

#define LDA 40   // A-tile padded row stride in halfs (80 B)
#define WSC 128  // s-rows per k_wsum block

// ws layout: [0,512K) packed Wc fp16; [512K,640K) cbar f32 [B][D]; [640K,640K+4) mask count
#define WS_CBAR_OFF (512 * 1024)
#define WS_CNT_OFF  (640 * 1024)

// ---------------------------------------------------------------------------
// K0: pack Wc (fp32 [H][D]) -> fp16 in MFMA-fragment order.
//   slot = kt*2048 + hg*64 + lane ; holds Wc[hg*16 + (lane&15)][kt*32 + (lane>>4)*8 + j]
// ---------------------------------------------------------------------------
__global__ __launch_bounds__(256) void k_pack_wc(
        const float* __restrict__ Wc, _Float16* __restrict__ wsB) {
    const int slot = blockIdx.x * 256 + threadIdx.x;   // 0..32767
    const int kt   = slot >> 11;
    const int rem  = slot & 2047;
    const int hg   = rem >> 6;
    const int lane = rem & 63;
    const int h  = hg * 16 + (lane & 15);
    const int k0 = kt * 32 + (lane >> 4) * 8;
    const float* src = Wc + (size_t)h * D + k0;
    float4 f0 = *(const float4*)src;
    float4 f1 = *(const float4*)(src + 4);
    f16x8 v;
    v[0] = (_Float16)f0.x; v[1] = (_Float16)f0.y;
    v[2] = (_Float16)f0.z; v[3] = (_Float16)f0.w;
    v[4] = (_Float16)f1.x; v[5] = (_Float16)f1.y;
    v[6] = (_Float16)f1.z; v[7] = (_Float16)f1.w;
    *(f16x8*)(wsB + (size_t)slot * 8) = v;
}

// ---------------------------------------------------------------------------
// K0b: global mask count (once, not per-softmax-block)
// ---------------------------------------------------------------------------
__global__ __launch_bounds__(256) void k_mask_count(
        const int* __restrict__ mask, int* __restrict__ cnt) {
    const int base = blockIdx.x * 256 + threadIdx.x;
    int local = 0;
    for (int i = base; i < B * S; i += 256 * 64) local += (mask[i] != 0) ? 1 : 0;
    #pragma unroll
    for (int off = 32; off; off >>= 1) local += __shfl_down(local, off, 64);
    if ((threadIdx.x & 63) == 0 && local) atomicAdd(cnt, local);
}

// ---------------------------------------------------------------------------
// K1: inp = input @ W_in^T + b_in   -> stored temporarily in d_out hidden region
// ---------------------------------------------------------------------------
__global__ __launch_bounds__(256) void k_input_linear(
        const float* __restrict__ input,
        const float* __restrict__ W_in,
        const float* __restrict__ b_in,
        float* __restrict__ out_inp) {
    const int b = blockIdx.x;
    const int tid = threadIdx.x;
    __shared__ float xrow[D];
    for (int d = tid; d < D; d += 256) xrow[d] = input[(size_t)b * D + d];
    __syncthreads();
    for (int h = tid; h < H; h += 256) {
        const float* w = W_in + (size_t)h * D;
        float acc = 0.f;
        #pragma unroll 4
        for (int d = 0; d < D; d += 4) {
            float4 wv = *(const float4*)(w + d);
            acc += wv.x * xrow[d] + wv.y * xrow[d + 1] + wv.z * xrow[d + 2] + wv.w * xrow[d + 3];
        }
        out_inp[(size_t)b * H + h] = acc + b_in[h];
    }
}

// ---------------------------------------------------------------------------
// K2 (MFMA): fused ctx-GEMM + tanh + V-reduce.
//   Grid: (b, s-tile of 128, h-half of 256). 512 threads = 8 waves (2s x 4h),
//   wave tile 64s x 64h -> acc 64 regs. A (ctx->fp16) via small LDS tile;
//   B fragments loaded straight from packed-Wc global (L2-resident).
//   Two h-half blocks atomicAdd their V-reduction into pre-zeroed att.
// ---------------------------------------------------------------------------
__global__ __launch_bounds__(512, 4) void k_energy(
        const float* __restrict__ ctx,
        const _Float16* __restrict__ WcP,
        const float* __restrict__ bc,
        const float* __restrict__ inp,
        const float* __restrict__ V,
        float* __restrict__ att) {
    __shared__ alignas(16) _Float16 Alds[128 * LDA];   // 10240 B
    __shared__ float red[4][128];

    const int tid = threadIdx.x;
    const int b  = blockIdx.x >> 5;
    const int s0 = ((blockIdx.x >> 1) & 15) << 7;
    const int h0 = (blockIdx.x & 1) << 8;              // 0 or 256

    // staging roles (A): 4 threads per row, 8 halfs each
    const int arow = tid >> 2;      // 0..127
    const int akq  = tid & 3;
    // compute roles
    const int lane = tid & 63;
    const int w    = tid >> 6;
    const int wsh  = w & 1;         // s-half of block
    const int wh   = w >> 1;        // 0..3: 64-h slice within this h-half
    const int lrow = lane & 15;
    const int kblk = lane >> 4;

    f32x4 acc[4][4] = {};

    const size_t ctx_row0 = ((size_t)b * S + s0 + arow) * D;
    const _Float16* Abase = &Alds[(wsh * 64 + lrow) * LDA + kblk * 8];
    // B fragment base for this wave: hg = (h0>>4) + wh*4 + n
    const _Float16* Bbase = WcP + ((size_t)((h0 >> 4) + wh * 4) * 64 + lane) * 8;

    // ---- prologue: stage A(0) ----
    {
        float4 f0 = *(const float4*)(ctx + ctx_row0 + akq * 8);
        float4 f1 = *(const float4*)(ctx + ctx_row0 + akq * 8 + 4);
        union { fp16x2 h2[4]; f16x8 v; } u;
        u.h2[0] = __builtin_amdgcn_cvt_pkrtz(f0.x, f0.y);
        u.h2[1] = __builtin_amdgcn_cvt_pkrtz(f0.z, f0.w);
        u.h2[2] = __builtin_amdgcn_cvt_pkrtz(f1.x, f1.y);
        u.h2[3] = __builtin_amdgcn_cvt_pkrtz(f1.z, f1.w);
        *(f16x8*)&Alds[arow * LDA + akq * 8] = u.v;
    }

    #pragma unroll 1
    for (int kt = 0; kt < 16; ++kt) {
        __syncthreads();   // A(kt) visible

        // B fragments for this K-step: direct from L2, coalesced
        f16x8 bfr[4];
        #pragma unroll
        for (int n = 0; n < 4; ++n)
            bfr[n] = *(const f16x8*)(Bbase + ((size_t)kt * 2048 + n * 64) * 8);

        // T14: issue next A tile loads early
        float4 nf0, nf1;
        if (kt < 15) {
            const float* asrc = ctx + ctx_row0 + (kt + 1) * 32 + akq * 8;
            nf0 = *(const float4*)asrc;
            nf1 = *(const float4*)(asrc + 4);
        }

        f16x8 afr[4];
        #pragma unroll
        for (int m = 0; m < 4; ++m)
            afr[m] = *(const f16x8*)(Abase + m * 16 * LDA);

        #pragma unroll
        for (int m = 0; m < 4; ++m)
            #pragma unroll
            for (int n = 0; n < 4; ++n)
                acc[m][n] = __builtin_amdgcn_mfma_f32_16x16x32_f16(afr[m], bfr[n], acc[m][n], 0, 0, 0);

        __syncthreads();   // A(kt) consumed

        if (kt < 15) {
            union { fp16x2 h2[4]; f16x8 v; } u;
            u.h2[0] = __builtin_amdgcn_cvt_pkrtz(nf0.x, nf0.y);
            u.h2[1] = __builtin_amdgcn_cvt_pkrtz(nf0.z, nf0.w);
            u.h2[2] = __builtin_amdgcn_cvt_pkrtz(nf1.x, nf1.y);
            u.h2[3] = __builtin_amdgcn_cvt_pkrtz(nf1.z, nf1.w);
            *(f16x8*)&Alds[arow * LDA + akq * 8] = u.v;
        }
    }

    // ---- epilogue: tanh + V weighting; reduce over the 64 h of this wave ----
    float ps[4][4] = {};   // [m][reg]
    #pragma unroll
    for (int n = 0; n < 4; ++n) {
        const int h = h0 + wh * 64 + n * 16 + lrow;
        const float ib = inp[(size_t)b * H + h] + bc[h];
        const float v = V[h];
        #pragma unroll
        for (int m = 0; m < 4; ++m)
            #pragma unroll
            for (int r = 0; r < 4; ++r) {
                const float x = acc[m][n][r] + ib;
                const float t = 1.f - 2.f / (1.f + __expf(2.f * x));
                ps[m][r] += v * t;
            }
    }
    #pragma unroll
    for (int off = 1; off < 16; off <<= 1)
        #pragma unroll
        for (int m = 0; m < 4; ++m)
            #pragma unroll
            for (int r = 0; r < 4; ++r)
                ps[m][r] += __shfl_xor(ps[m][r], off, 64);
    if (lrow == 0) {
        #pragma unroll
        for (int m = 0; m < 4; ++m)
            #pragma unroll
            for (int r = 0; r < 4; ++r)
                red[wh][wsh * 64 + m * 16 + kblk * 4 + r] = ps[m][r];
    }
    __syncthreads();
    if (tid < 128) {
        const float sum = red[0][tid] + red[1][tid] + red[2][tid] + red[3][tid];
        atomicAdd(att + (size_t)b * S + s0 + tid, sum);
    }
}

// ---------------------------------------------------------------------------
// K4: mask branch + softmax per row (in place in the alpha region).
// ---------------------------------------------------------------------------
__global__ __launch_bounds__(256) void k_softmax(
        const int* __restrict__ mask,
        const float* __restrict__ amask,
        const int* __restrict__ cnt,
        float* __restrict__ att) {
    const int b = blockIdx.x;
    const int tid = threadIdx.x;
    __shared__ float sh[S];
    __shared__ float fredm[4];
    __shared__ float freds[4];

    const int n_true = *cnt;
    const bool inf_branch = (n_true > 0) && (n_true == S);

    const float NEG_INF = -__builtin_inff();
    for (int s = tid; s < S; s += 256) {
        const float raw = att[(size_t)b * S + s];
        float v;
        if (inf_branch)
            v = mask[(size_t)b * S + s] ? NEG_INF : raw;
        else
            v = raw * amask[(size_t)b * S + s];
        sh[s] = v;
    }
    __syncthreads();

    float mx = NEG_INF;
    for (int s = tid; s < S; s += 256) mx = fmaxf(mx, sh[s]);
    #pragma unroll
    for (int off = 32; off; off >>= 1) mx = fmaxf(mx, __shfl_down(mx, off, 64));
    if ((tid & 63) == 0) fredm[tid >> 6] = mx;
    __syncthreads();
    mx = fmaxf(fmaxf(fredm[0], fredm[1]), fmaxf(fredm[2], fredm[3]));

    float lsum = 0.f;
    for (int s = tid; s < S; s += 256) {
        const float e = expf(sh[s] - mx);
        sh[s] = e;
        lsum += e;
    }
    #pragma unroll
    for (int off = 32; off; off >>= 1) lsum += __shfl_down(lsum, off, 64);
    if ((tid & 63) == 0) freds[tid >> 6] = lsum;
    __syncthreads();
    const float total = freds[0] + freds[1] + freds[2] + freds[3];
    const float rinv = 1.f / total;

    for (int s = tid; s < S; s += 256)
        att[(size_t)b * S + s] = sh[s] * rinv;
}

// ---------------------------------------------------------------------------
// K5: cbar[b,:] += sum_s alpha[b,s] * ctx[b,s,:]  (streaming, atomic partials)
// ---------------------------------------------------------------------------
__global__ __launch_bounds__(256) void k_wsum(
        const float* __restrict__ ctx,
        const float* __restrict__ alpha,
        float* __restrict__ cbar) {
    const int chunk = blockIdx.x & 15;
    const int b = blockIdx.x >> 4;
    const int s0 = chunk * WSC;
    const int tid = threadIdx.x;
    __shared__ float al[WSC];
    if (tid < WSC) al[tid] = alpha[(size_t)b * S + s0 + tid];
    __syncthreads();

    const int half = tid >> 7;
    const int dq = (tid & 127) * 4;
    const float* base = ctx + ((size_t)b * S + s0 + half) * D + dq;
    float4 acc = {0.f, 0.f, 0.f, 0.f};
    #pragma unroll 4
    for (int i = 0; i < WSC / 2; ++i) {
        float4 v = *(const float4*)(base + (size_t)i * 2 * D);
        const float a = al[i * 2 + half];
        acc.x += a * v.x; acc.y += a * v.y; acc.z += a * v.z; acc.w += a * v.w;
    }
    float* dst = cbar + (size_t)b * D + dq;
    atomicAdd(dst + 0, acc.x);
    atomicAdd(dst + 1, acc.y);
    atomicAdd(dst + 2, acc.z);
    atomicAdd(dst + 3, acc.w);
}

// ---------------------------------------------------------------------------
// K6: hidden = Wc @ cbar + bc   (tiny GEMV per batch)
// ---------------------------------------------------------------------------
__global__ __launch_bounds__(256) void k_out(
        const float* __restrict__ cbar,
        const float* __restrict__ Wc,
        const float* __restrict__ bc,
        float* __restrict__ hidden) {
    const int b = blockIdx.x;
    const int tid = threadIdx.x;
    __shared__ float cb[D];
    for (int d = tid; d < D; d += 256) cb[d] = cbar[(size_t)b * D + d];
    __syncthreads();
    for (int h = tid; h < H; h += 256) {
        const float* w = Wc + (size_t)h * D;
        float acc = 0.f;
        #pragma unroll 4
        for (int d = 0; d < D; d += 4) {
            float4 wv = *(const float4*)(w + d);
            acc += wv.x * cb[d] + wv.y * cb[d + 1] + wv.z * cb[d + 2] + wv.w * cb[d + 3];
        }
        hidden[(size_t)b * H + h] = acc + bc[h];
    }
}

// ---------------------------------------------------------------------------
extern "C" void kernel_launch(void* const* d_in, const int* in_sizes, int n_in,
                              void* d_out, int out_size, void* d_ws, size_t ws_size,
                              hipStream_t stream) {
    const float* input = (const float*)d_in[0];
    const float* ctx   = (const float*)d_in[1];
    const float* amask = (const float*)d_in[2];
    const float* W_in  = (const float*)d_in[3];
    const float* b_in  = (const float*)d_in[4];
    const float* W_ctx = (const float*)d_in[5];
    const float* b_ctx = (const float*)d_in[6];
    const float* V     = (const float*)d_in[7];
    const int*   mask  = (const int*)d_in[8];

    float* out = (float*)d_out;
    float* hidden = out;            // [B,H]
    float* alpha  = out + B * H;    // [B,S]

    _Float16* wsB  = (_Float16*)d_ws;
    float*    cbar = (float*)((char*)d_ws + WS_CBAR_OFF);
    int*      cnt  = (int*)((char*)d_ws + WS_CNT_OFF);

    // K0: pack Wc -> fp16 fragment order; K0b: mask count
    k_pack_wc<<<dim3(128), dim3(256), 0, stream>>>(W_ctx, wsB);
    (void)hipMemsetAsync(cnt, 0, sizeof(int), stream);
    k_mask_count<<<dim3(64), dim3(256), 0, stream>>>(mask, cnt);

    // K1: inp staged in the hidden region (overwritten later by real hidden)
    k_input_linear<<<dim3(B), dim3(256), 0, stream>>>(input, W_in, b_in, hidden);

    // K2: fused energy GEMM -> att (alpha region; zeroed for h-half atomics)
    (void)hipMemsetAsync(alpha, 0, (size_t)B * S * sizeof(float), stream);
    k_energy<<<dim3((B * S) / 128 * 2), dim3(512), 0, stream>>>(
        ctx, wsB, b_ctx, hidden, V, alpha);

    // K4: mask branch + softmax in place -> alpha final
    k_softmax<<<dim3(B), dim3(256), 0, stream>>>(mask, amask, cnt, alpha);

    // K5: weighted context sum -> cbar (zeroed first)
    (void)hipMemsetAsync(cbar, 0, (size_t)B * D * sizeof(float), stream);
    k_wsum<<<dim3(16 * B), dim3(256), 0, stream>>>(ctx, alpha, cbar);

    // K6: hidden = Wc @ cbar + bc
    k_out<<<dim3(B), dim3(256), 0, stream>>>(cbar, W_ctx, b_ctx, hidden);
}

// Round 6
// 245.359 us; speedup vs baseline: 4.8242x; 1.0458x over previous
//
#include <hip/hip_runtime.h>
#include <math.h>

#define B 64
#define S 2048
#define D 512
#define H 512

typedef _Float16 f16x8 __attribute__((ext_vector_type(8)));
typedef _Float16 f16x4 __attribute__((ext_vector_type(4)));
typedef __fp16 fp16x2 __attribute__((ext_vector_type(2)));
typedef float f32x4 __attribute__((ext_vector_type(4)));

#define LDA 40   // A-tile row stride in halfs (80 B: 16B-aligned frags, <=2-way banks)
#define WSC 128  // s-rows per k_wsum block

// ws layout: [0,512K) packed Wc fp16; [512K,640K) cbar f32 [B][D]; [640K,640K+4) mask count
#define WS_CBAR_OFF (512 * 1024)
#define WS_CNT_OFF  (640 * 1024)

// ---------------------------------------------------------------------------
// K0: pack Wc (fp32 [H][D]) -> fp16 in MFMA-fragment order.
//   slot = kt*2048 + hg*64 + lane ; holds Wc[hg*16 + (lane&15)][kt*32 + (lane>>4)*8 + j]
// ---------------------------------------------------------------------------
__global__ __launch_bounds__(256) void k_pack_wc(
        const float* __restrict__ Wc, _Float16* __restrict__ wsB) {
    const int slot = blockIdx.x * 256 + threadIdx.x;   // 0..32767
    const int kt   = slot >> 11;
    const int rem  = slot & 2047;
    const int hg   = rem >> 6;
    const int lane = rem & 63;
    const int h  = hg * 16 + (lane & 15);
    const int k0 = kt * 32 + (lane >> 4) * 8;
    const float* src = Wc + (size_t)h * D + k0;
    float4 f0 = *(const float4*)src;
    float4 f1 = *(const float4*)(src + 4);
    f16x8 v;
    v[0] = (_Float16)f0.x; v[1] = (_Float16)f0.y;
    v[2] = (_Float16)f0.z; v[3] = (_Float16)f0.w;
    v[4] = (_Float16)f1.x; v[5] = (_Float16)f1.y;
    v[6] = (_Float16)f1.z; v[7] = (_Float16)f1.w;
    *(f16x8*)(wsB + (size_t)slot * 8) = v;
}

// ---------------------------------------------------------------------------
// K0b: global mask count (once)
// ---------------------------------------------------------------------------
__global__ __launch_bounds__(256) void k_mask_count(
        const int* __restrict__ mask, int* __restrict__ cnt) {
    const int base = blockIdx.x * 256 + threadIdx.x;
    int local = 0;
    for (int i = base; i < B * S; i += 256 * 64) local += (mask[i] != 0) ? 1 : 0;
    #pragma unroll
    for (int off = 32; off; off >>= 1) local += __shfl_down(local, off, 64);
    if ((threadIdx.x & 63) == 0 && local) atomicAdd(cnt, local);
}

// ---------------------------------------------------------------------------
// K1: inp = input @ W_in^T + b_in   -> staged in d_out hidden region
// ---------------------------------------------------------------------------
__global__ __launch_bounds__(256) void k_input_linear(
        const float* __restrict__ input,
        const float* __restrict__ W_in,
        const float* __restrict__ b_in,
        float* __restrict__ out_inp) {
    const int b = blockIdx.x;
    const int tid = threadIdx.x;
    __shared__ float xrow[D];
    for (int d = tid; d < D; d += 256) xrow[d] = input[(size_t)b * D + d];
    __syncthreads();
    for (int h = tid; h < H; h += 256) {
        const float* w = W_in + (size_t)h * D;
        float acc = 0.f;
        #pragma unroll 4
        for (int d = 0; d < D; d += 4) {
            float4 wv = *(const float4*)(w + d);
            acc += wv.x * xrow[d] + wv.y * xrow[d + 1] + wv.z * xrow[d + 2] + wv.w * xrow[d + 3];
        }
        out_inp[(size_t)b * H + h] = acc + b_in[h];
    }
}

// ---------------------------------------------------------------------------
// K2 (MFMA): fused ctx-GEMM + tanh + V-reduce.
//   Block: 64 s-rows x FULL H=512 (ctx read exactly once). 8 waves, wave
//   tile 64s x 64h (wave w owns h in [w*64, w*64+64)). A tile (64x32 fp16)
//   double-buffered in LDS -> ONE barrier per K-step. B frags direct from
//   packed-Wc global (L2-resident). Direct att store, no atomics.
// ---------------------------------------------------------------------------
__global__ __launch_bounds__(512, 4) void k_energy(
        const float* __restrict__ ctx,
        const _Float16* __restrict__ WcP,
        const float* __restrict__ bc,
        const float* __restrict__ inp,
        const float* __restrict__ V,
        float* __restrict__ att) {
    __shared__ alignas(16) _Float16 Alds[2][64 * LDA];   // 2 x 5120 B
    __shared__ float red[8][64];

    const int tid = threadIdx.x;
    const int b  = blockIdx.x >> 5;             // 32 s-tiles per batch
    const int s0 = (blockIdx.x & 31) << 6;

    // staging roles: 8 threads per row, 4 floats (8 B fp16) each
    const int arow = tid >> 3;      // 0..63
    const int akq  = tid & 7;       // 0..7 -> k offset akq*4
    // compute roles
    const int lane = tid & 63;
    const int w    = tid >> 6;      // 0..7: h-slice
    const int lrow = lane & 15;
    const int kblk = lane >> 4;

    f32x4 acc[4][4] = {};

    const float* ctx_src = ctx + ((size_t)b * S + s0 + arow) * D + akq * 4;
    const _Float16* Abase = &Alds[0][lrow * LDA + kblk * 8];
    const _Float16* Bbase = WcP + ((size_t)(w * 4) * 64 + lane) * 8;

    // ---- prologue: stage A(0) into buf 0 ----
    {
        float4 f = *(const float4*)ctx_src;
        union { fp16x2 h2[2]; f16x4 v; } u;
        u.h2[0] = __builtin_amdgcn_cvt_pkrtz(f.x, f.y);
        u.h2[1] = __builtin_amdgcn_cvt_pkrtz(f.z, f.w);
        *(f16x4*)&Alds[0][arow * LDA + akq * 4] = u.v;
    }
    __syncthreads();

    #pragma unroll 1
    for (int kt = 0; kt < 16; ++kt) {
        const int cur = kt & 1;

        // T14: issue next A tile load early (consumed after the MFMAs)
        float4 nf;
        if (kt < 15) nf = *(const float4*)(ctx_src + (kt + 1) * 32);

        // B frags for this K-step (L2)
        f16x8 bfr[4];
        #pragma unroll
        for (int n = 0; n < 4; ++n)
            bfr[n] = *(const f16x8*)(Bbase + ((size_t)kt * 2048 + n * 64) * 8);

        // A frags from LDS buf[cur]
        f16x8 afr[4];
        #pragma unroll
        for (int m = 0; m < 4; ++m)
            afr[m] = *(const f16x8*)(Abase + cur * (64 * LDA) + m * 16 * LDA);

        #pragma unroll
        for (int m = 0; m < 4; ++m)
            #pragma unroll
            for (int n = 0; n < 4; ++n)
                acc[m][n] = __builtin_amdgcn_mfma_f32_16x16x32_f16(afr[m], bfr[n], acc[m][n], 0, 0, 0);

        // write next A tile to the other buffer
        if (kt < 15) {
            union { fp16x2 h2[2]; f16x4 v; } u;
            u.h2[0] = __builtin_amdgcn_cvt_pkrtz(nf.x, nf.y);
            u.h2[1] = __builtin_amdgcn_cvt_pkrtz(nf.z, nf.w);
            *(f16x4*)&Alds[cur ^ 1][arow * LDA + akq * 4] = u.v;
        }
        __syncthreads();
    }

    // ---- epilogue: tanh + V weighting; reduce over this wave's 64 h ----
    float ps[4][4] = {};   // [m][reg]
    #pragma unroll
    for (int n = 0; n < 4; ++n) {
        const int h = w * 64 + n * 16 + lrow;
        const float ib = inp[(size_t)b * H + h] + bc[h];
        const float v = V[h];
        #pragma unroll
        for (int m = 0; m < 4; ++m)
            #pragma unroll
            for (int r = 0; r < 4; ++r) {
                const float x = acc[m][n][r] + ib;
                const float t = 1.f - 2.f / (1.f + __expf(2.f * x));
                ps[m][r] += v * t;
            }
    }
    #pragma unroll
    for (int off = 1; off < 16; off <<= 1)
        #pragma unroll
        for (int m = 0; m < 4; ++m)
            #pragma unroll
            for (int r = 0; r < 4; ++r)
                ps[m][r] += __shfl_xor(ps[m][r], off, 64);
    if (lrow == 0) {
        #pragma unroll
        for (int m = 0; m < 4; ++m)
            #pragma unroll
            for (int r = 0; r < 4; ++r)
                red[w][m * 16 + kblk * 4 + r] = ps[m][r];
    }
    __syncthreads();
    if (tid < 64) {
        float sum = 0.f;
        #pragma unroll
        for (int i = 0; i < 8; ++i) sum += red[i][tid];
        att[(size_t)b * S + s0 + tid] = sum;
    }
}

// ---------------------------------------------------------------------------
// K4: mask branch + softmax per row (in place in the alpha region).
// ---------------------------------------------------------------------------
__global__ __launch_bounds__(256) void k_softmax(
        const int* __restrict__ mask,
        const float* __restrict__ amask,
        const int* __restrict__ cnt,
        float* __restrict__ att) {
    const int b = blockIdx.x;
    const int tid = threadIdx.x;
    __shared__ float sh[S];
    __shared__ float fredm[4];
    __shared__ float freds[4];

    const int n_true = *cnt;
    const bool inf_branch = (n_true > 0) && (n_true == S);

    const float NEG_INF = -__builtin_inff();
    for (int s = tid; s < S; s += 256) {
        const float raw = att[(size_t)b * S + s];
        float v;
        if (inf_branch)
            v = mask[(size_t)b * S + s] ? NEG_INF : raw;
        else
            v = raw * amask[(size_t)b * S + s];
        sh[s] = v;
    }
    __syncthreads();

    float mx = NEG_INF;
    for (int s = tid; s < S; s += 256) mx = fmaxf(mx, sh[s]);
    #pragma unroll
    for (int off = 32; off; off >>= 1) mx = fmaxf(mx, __shfl_down(mx, off, 64));
    if ((tid & 63) == 0) fredm[tid >> 6] = mx;
    __syncthreads();
    mx = fmaxf(fmaxf(fredm[0], fredm[1]), fmaxf(fredm[2], fredm[3]));

    float lsum = 0.f;
    for (int s = tid; s < S; s += 256) {
        const float e = expf(sh[s] - mx);
        sh[s] = e;
        lsum += e;
    }
    #pragma unroll
    for (int off = 32; off; off >>= 1) lsum += __shfl_down(lsum, off, 64);
    if ((tid & 63) == 0) freds[tid >> 6] = lsum;
    __syncthreads();
    const float total = freds[0] + freds[1] + freds[2] + freds[3];
    const float rinv = 1.f / total;

    for (int s = tid; s < S; s += 256)
        att[(size_t)b * S + s] = sh[s] * rinv;
}

// ---------------------------------------------------------------------------
// K5: cbar[b,:] += sum_s alpha[b,s] * ctx[b,s,:]  (streaming, atomic partials)
// ---------------------------------------------------------------------------
__global__ __launch_bounds__(256) void k_wsum(
        const float* __restrict__ ctx,
        const float* __restrict__ alpha,
        float* __restrict__ cbar) {
    const int chunk = blockIdx.x & 15;
    const int b = blockIdx.x >> 4;
    const int s0 = chunk * WSC;
    const int tid = threadIdx.x;
    __shared__ float al[WSC];
    if (tid < WSC) al[tid] = alpha[(size_t)b * S + s0 + tid];
    __syncthreads();

    const int half = tid >> 7;
    const int dq = (tid & 127) * 4;
    const float* base = ctx + ((size_t)b * S + s0 + half) * D + dq;
    float4 acc = {0.f, 0.f, 0.f, 0.f};
    #pragma unroll 4
    for (int i = 0; i < WSC / 2; ++i) {
        float4 v = *(const float4*)(base + (size_t)i * 2 * D);
        const float a = al[i * 2 + half];
        acc.x += a * v.x; acc.y += a * v.y; acc.z += a * v.z; acc.w += a * v.w;
    }
    float* dst = cbar + (size_t)b * D + dq;
    atomicAdd(dst + 0, acc.x);
    atomicAdd(dst + 1, acc.y);
    atomicAdd(dst + 2, acc.z);
    atomicAdd(dst + 3, acc.w);
}

// ---------------------------------------------------------------------------
// K6: hidden = Wc @ cbar + bc   (tiny GEMV per batch)
// ---------------------------------------------------------------------------
__global__ __launch_bounds__(256) void k_out(
        const float* __restrict__ cbar,
        const float* __restrict__ Wc,
        const float* __restrict__ bc,
        float* __restrict__ hidden) {
    const int b = blockIdx.x;
    const int tid = threadIdx.x;
    __shared__ float cb[D];
    for (int d = tid; d < D; d += 256) cb[d] = cbar[(size_t)b * D + d];
    __syncthreads();
    for (int h = tid; h < H; h += 256) {
        const float* w = Wc + (size_t)h * D;
        float acc = 0.f;
        #pragma unroll 4
        for (int d = 0; d < D; d += 4) {
            float4 wv = *(const float4*)(w + d);
            acc += wv.x * cb[d] + wv.y * cb[d + 1] + wv.z * cb[d + 2] + wv.w * cb[d + 3];
        }
        hidden[(size_t)b * H + h] = acc + bc[h];
    }
}

// ---------------------------------------------------------------------------
extern "C" void kernel_launch(void* const* d_in, const int* in_sizes, int n_in,
                              void* d_out, int out_size, void* d_ws, size_t ws_size,
                              hipStream_t stream) {
    const float* input = (const float*)d_in[0];
    const float* ctx   = (const float*)d_in[1];
    const float* amask = (const float*)d_in[2];
    const float* W_in  = (const float*)d_in[3];
    const float* b_in  = (const float*)d_in[4];
    const float* W_ctx = (const float*)d_in[5];
    const float* b_ctx = (const float*)d_in[6];
    const float* V     = (const float*)d_in[7];
    const int*   mask  = (const int*)d_in[8];

    float* out = (float*)d_out;
    float* hidden = out;            // [B,H]
    float* alpha  = out + B * H;    // [B,S]

    _Float16* wsB  = (_Float16*)d_ws;
    float*    cbar = (float*)((char*)d_ws + WS_CBAR_OFF);
    int*      cnt  = (int*)((char*)d_ws + WS_CNT_OFF);

    // K0: pack Wc -> fp16 fragment order; K0b: mask count
    k_pack_wc<<<dim3(128), dim3(256), 0, stream>>>(W_ctx, wsB);
    (void)hipMemsetAsync(cnt, 0, sizeof(int), stream);
    k_mask_count<<<dim3(64), dim3(256), 0, stream>>>(mask, cnt);

    // K1: inp staged in the hidden region (overwritten later by real hidden)
    k_input_linear<<<dim3(B), dim3(256), 0, stream>>>(input, W_in, b_in, hidden);

    // K2: fused energy GEMM -> att (alpha region, direct store)
    k_energy<<<dim3(B * S / 64), dim3(512), 0, stream>>>(
        ctx, wsB, b_ctx, hidden, V, alpha);

    // K4: mask branch + softmax in place -> alpha final
    k_softmax<<<dim3(B), dim3(256), 0, stream>>>(mask, amask, cnt, alpha);

    // K5: weighted context sum -> cbar (zeroed first)
    (void)hipMemsetAsync(cbar, 0, (size_t)B * D * sizeof(float), stream);
    k_wsum<<<dim3(16 * B), dim3(256), 0, stream>>>(ctx, alpha, cbar);

    // K6: hidden = Wc @ cbar + bc
    k_out<<<dim3(B), dim3(256), 0, stream>>>(cbar, W_ctx, b_ctx, hidden);
}